// Round 2
// baseline (989.630 us; speedup 1.0000x reference)
//
#include <hip/hip_runtime.h>
#include <hip/hip_bf16.h>

#define BB 2
#define LL 2048
#define DD 1024
#define HH 16
#define HDm 64
#define BHm 32

typedef __attribute__((ext_vector_type(8))) short short8;
typedef __attribute__((ext_vector_type(4))) float floatx4;

__device__ __forceinline__ unsigned short f2bf(float f) {
  union { float f; unsigned int u; } v; v.f = f;
  unsigned int r = v.u + 0x7fffu + ((v.u >> 16) & 1u);
  return (unsigned short)(r >> 16);
}

__device__ __forceinline__ short8 pack8(float4 a, float4 b) {
  short8 s;
  s[0]=(short)f2bf(a.x); s[1]=(short)f2bf(a.y); s[2]=(short)f2bf(a.z); s[3]=(short)f2bf(a.w);
  s[4]=(short)f2bf(b.x); s[5]=(short)f2bf(b.y); s[6]=(short)f2bf(b.z); s[7]=(short)f2bf(b.w);
  return s;
}

// ---------------- Kernel 1: QKV projections ----------------
// C = X @ W^T (NT GEMM), X f32 (4096x1024), W f32 (1024x1024), out bf16.
// which=0 -> Qh[b][h][l][hd], which=1 -> Kh same, which=2 -> Vt[b][h][hd][l]
__global__ __launch_bounds__(256) void k_proj_qkv(
    const float* __restrict__ Xq, const float* __restrict__ Xk, const float* __restrict__ Xv,
    const float* __restrict__ Wq, const float* __restrict__ Wk, const float* __restrict__ Wv,
    unsigned short* __restrict__ Qh, unsigned short* __restrict__ Kh,
    unsigned short* __restrict__ Vt)
{
  const int which = blockIdx.z;
  const float* X = (which == 0) ? Xq : ((which == 1) ? Xk : Xv);
  const float* W = (which == 0) ? Wq : ((which == 1) ? Wk : Wv);

  const int I0 = blockIdx.x * 64;
  const int N0 = blockIdx.y * 64;
  const int tid = threadIdx.x;
  const int lane = tid & 63;
  const int w = tid >> 6;
  const int colb = lane & 15;
  const int rowb = (lane >> 4) * 4;
  const int kseg = (lane >> 4) * 8;

  __shared__ unsigned short Al[64 * 40];  // +8 pad: stride 80B, 16B aligned
  __shared__ unsigned short Bl[64 * 40];

  floatx4 acc[4] = {};
  const int sr = tid >> 2;         // staging row 0..63
  const int sc = (tid & 3) * 8;    // staging col 0,8,16,24

  for (int k0 = 0; k0 < DD; k0 += 32) {
    const float4* xa = reinterpret_cast<const float4*>(X + (size_t)(I0 + sr) * DD + k0 + sc);
    float4 a0 = xa[0], a1 = xa[1];
    const float4* xb = reinterpret_cast<const float4*>(W + (size_t)(N0 + sr) * DD + k0 + sc);
    float4 b0 = xb[0], b1 = xb[1];
    *reinterpret_cast<short8*>(&Al[sr * 40 + sc]) = pack8(a0, a1);
    *reinterpret_cast<short8*>(&Bl[sr * 40 + sc]) = pack8(b0, b1);
    __syncthreads();

    short8 af = *reinterpret_cast<const short8*>(&Al[(w * 16 + colb) * 40 + kseg]);
#pragma unroll
    for (int nt = 0; nt < 4; ++nt) {
      short8 bf = *reinterpret_cast<const short8*>(&Bl[(nt * 16 + colb) * 40 + kseg]);
      acc[nt] = __builtin_amdgcn_mfma_f32_16x16x32_bf16(af, bf, acc[nt], 0, 0, 0);
    }
    __syncthreads();
  }

#pragma unroll
  for (int nt = 0; nt < 4; ++nt) {
    int col = N0 + nt * 16 + colb;          // 0..1023
    int h = col >> 6, hd = col & 63;
#pragma unroll
    for (int rr = 0; rr < 4; ++rr) {
      int row = I0 + w * 16 + rowb + rr;    // 0..4095
      int b = row >> 11, l = row & 2047;
      unsigned short val = f2bf(acc[nt][rr]);
      if (which == 0)
        Qh[(((size_t)(b * HH + h)) * LL + l) * HDm + hd] = val;
      else if (which == 1)
        Kh[(((size_t)(b * HH + h)) * LL + l) * HDm + hd] = val;
      else
        Vt[(((size_t)(b * HH + h)) * HDm + hd) * LL + l] = val;
    }
  }
}

// ---------------- Kernel 2: fused causal attention ----------------
// grid (32 qtiles, 32 bh); block 256 = 4 waves; wave w owns q-rows Q0+w*16..+15
__global__ __launch_bounds__(256) void k_attn(
    const unsigned short* __restrict__ Qh,
    const unsigned short* __restrict__ Kh,
    const unsigned short* __restrict__ Vt,
    float* __restrict__ attn,               // (BH, L, L) f32
    unsigned short* __restrict__ Ctx)       // (B, L, D) bf16
{
  const int qt = blockIdx.x;
  const int bh = blockIdx.y;
  const int b = bh >> 4, h = bh & 15;
  const int Q0 = qt * 64;
  const int tid = threadIdx.x;
  const int lane = tid & 63;
  const int w = tid >> 6;
  const int colb = lane & 15;
  const int rowb = (lane >> 4) * 4;
  const int kseg = (lane >> 4) * 8;
  const float scale = 0.125f;  // rsqrt(64)

  __shared__ unsigned short Pl[64 * 72];  // prob tile bf16, stride 144B (16B aligned)

  const unsigned short* Qbase = Qh + (size_t)bh * LL * HDm;
  const unsigned short* Kbase = Kh + (size_t)bh * LL * HDm;
  const unsigned short* Vbase = Vt + (size_t)bh * HDm * LL;

  const int qrow = Q0 + w * 16 + colb;
  short8 qf0 = *reinterpret_cast<const short8*>(Qbase + (size_t)qrow * HDm + kseg);
  short8 qf1 = *reinterpret_cast<const short8*>(Qbase + (size_t)qrow * HDm + 32 + kseg);

  float m[4], ssum[4];
#pragma unroll
  for (int rr = 0; rr < 4; ++rr) { m[rr] = -__builtin_huge_valf(); ssum[rr] = 0.f; }

  // ---- Pass A: online row max + sumexp (no storage) ----
  for (int kt = 0; kt <= qt; ++kt) {
    const int K0 = kt * 64;
    floatx4 sacc[4] = {};
#pragma unroll
    for (int nt = 0; nt < 4; ++nt) {
      const unsigned short* kp = Kbase + (size_t)(K0 + nt * 16 + colb) * HDm + kseg;
      short8 kf0 = *reinterpret_cast<const short8*>(kp);
      short8 kf1 = *reinterpret_cast<const short8*>(kp + 32);
      sacc[nt] = __builtin_amdgcn_mfma_f32_16x16x32_bf16(qf0, kf0, sacc[nt], 0, 0, 0);
      sacc[nt] = __builtin_amdgcn_mfma_f32_16x16x32_bf16(qf1, kf1, sacc[nt], 0, 0, 0);
    }
#pragma unroll
    for (int rr = 0; rr < 4; ++rr) {
      int row = Q0 + w * 16 + rowb + rr;
      float v0, v1, v2, v3;
      {
        float sv = sacc[0][rr] * scale;
        v0 = ((K0 + 0 * 16 + colb) > row || sv == 0.0f) ? -__builtin_huge_valf() : sv;
        sv = sacc[1][rr] * scale;
        v1 = ((K0 + 1 * 16 + colb) > row || sv == 0.0f) ? -__builtin_huge_valf() : sv;
        sv = sacc[2][rr] * scale;
        v2 = ((K0 + 2 * 16 + colb) > row || sv == 0.0f) ? -__builtin_huge_valf() : sv;
        sv = sacc[3][rr] * scale;
        v3 = ((K0 + 3 * 16 + colb) > row || sv == 0.0f) ? -__builtin_huge_valf() : sv;
      }
      float tmax = fmaxf(fmaxf(v0, v1), fmaxf(v2, v3));
#pragma unroll
      for (int d = 1; d < 16; d <<= 1) tmax = fmaxf(tmax, __shfl_xor(tmax, d, 64));
      float mnew = fmaxf(m[rr], tmax);
      float psum = __expf(v0 - mnew) + __expf(v1 - mnew) + __expf(v2 - mnew) + __expf(v3 - mnew);
#pragma unroll
      for (int d = 1; d < 16; d <<= 1) psum += __shfl_xor(psum, d, 64);
      ssum[rr] = ssum[rr] * __expf(m[rr] - mnew) + psum;
      m[rr] = mnew;
    }
  }

  float inv[4];
#pragma unroll
  for (int rr = 0; rr < 4; ++rr) inv[rr] = 1.0f / ssum[rr];

  floatx4 cacc[4] = {};

  // ---- Pass B: recompute, write normalized probs, accumulate PV ----
  for (int kt = 0; kt <= qt; ++kt) {
    const int K0 = kt * 64;
    floatx4 sacc[4] = {};
#pragma unroll
    for (int nt = 0; nt < 4; ++nt) {
      const unsigned short* kp = Kbase + (size_t)(K0 + nt * 16 + colb) * HDm + kseg;
      short8 kf0 = *reinterpret_cast<const short8*>(kp);
      short8 kf1 = *reinterpret_cast<const short8*>(kp + 32);
      sacc[nt] = __builtin_amdgcn_mfma_f32_16x16x32_bf16(qf0, kf0, sacc[nt], 0, 0, 0);
      sacc[nt] = __builtin_amdgcn_mfma_f32_16x16x32_bf16(qf1, kf1, sacc[nt], 0, 0, 0);
    }
#pragma unroll
    for (int nt = 0; nt < 4; ++nt) {
      int col = K0 + nt * 16 + colb;
#pragma unroll
      for (int rr = 0; rr < 4; ++rr) {
        int row = Q0 + w * 16 + rowb + rr;
        float sv = sacc[nt][rr] * scale;
        bool masked = (col > row) || (sv == 0.0f);
        float p = masked ? 0.0f : __expf(sv - m[rr]) * inv[rr];
        attn[((size_t)bh * LL + row) * LL + col] = p;
        Pl[(w * 16 + rowb + rr) * 72 + nt * 16 + colb] = f2bf(p);
      }
    }
    __syncthreads();
#pragma unroll
    for (int s = 0; s < 2; ++s) {
      short8 pf = *reinterpret_cast<const short8*>(&Pl[(w * 16 + colb) * 72 + s * 32 + kseg]);
#pragma unroll
      for (int nt = 0; nt < 4; ++nt) {
        const unsigned short* vp = Vbase + (size_t)(nt * 16 + colb) * LL + K0 + s * 32 + kseg;
        short8 vf = *reinterpret_cast<const short8*>(vp);
        cacc[nt] = __builtin_amdgcn_mfma_f32_16x16x32_bf16(pf, vf, cacc[nt], 0, 0, 0);
      }
    }
    __syncthreads();
  }

  // ---- zero-fill strictly-upper tiles (d_out is poisoned each run) ----
  const int C0 = (qt + 1) * 64;
  if (C0 < LL) {
    const int zl4 = (LL - C0) >> 2;
    const float4 z = make_float4(0.f, 0.f, 0.f, 0.f);
    for (int row = 0; row < 64; ++row) {
      float4* dst = reinterpret_cast<float4*>(attn + ((size_t)bh * LL + Q0 + row) * LL + C0);
      for (int c = tid; c < zl4; c += 256) dst[c] = z;
    }
  }

  // ---- write context tile (B, L, D) bf16 ----
#pragma unroll
  for (int nt = 0; nt < 4; ++nt) {
    int col = h * HDm + nt * 16 + colb;
#pragma unroll
    for (int rr = 0; rr < 4; ++rr) {
      int row = Q0 + w * 16 + rowb + rr;
      Ctx[((size_t)b * LL + row) * DD + col] = f2bf(cacc[nt][rr]);
    }
  }
}

// ---------------- Kernel 3: output projection ----------------
// Out = Ctx @ Wo^T ; Ctx bf16 (4096x1024), Wo f32, Out f32
__global__ __launch_bounds__(256) void k_out(
    const unsigned short* __restrict__ Ctx, const float* __restrict__ Wo,
    float* __restrict__ Out)
{
  const int I0 = blockIdx.x * 64;
  const int N0 = blockIdx.y * 64;
  const int tid = threadIdx.x;
  const int lane = tid & 63;
  const int w = tid >> 6;
  const int colb = lane & 15;
  const int rowb = (lane >> 4) * 4;
  const int kseg = (lane >> 4) * 8;

  __shared__ unsigned short Al[64 * 40];
  __shared__ unsigned short Bl[64 * 40];

  floatx4 acc[4] = {};
  const int sr = tid >> 2;
  const int sc = (tid & 3) * 8;

  for (int k0 = 0; k0 < DD; k0 += 32) {
    short8 av = *reinterpret_cast<const short8*>(Ctx + (size_t)(I0 + sr) * DD + k0 + sc);
    const float4* xb = reinterpret_cast<const float4*>(Wo + (size_t)(N0 + sr) * DD + k0 + sc);
    float4 b0 = xb[0], b1 = xb[1];
    *reinterpret_cast<short8*>(&Al[sr * 40 + sc]) = av;
    *reinterpret_cast<short8*>(&Bl[sr * 40 + sc]) = pack8(b0, b1);
    __syncthreads();

    short8 af = *reinterpret_cast<const short8*>(&Al[(w * 16 + colb) * 40 + kseg]);
#pragma unroll
    for (int nt = 0; nt < 4; ++nt) {
      short8 bf = *reinterpret_cast<const short8*>(&Bl[(nt * 16 + colb) * 40 + kseg]);
      acc[nt] = __builtin_amdgcn_mfma_f32_16x16x32_bf16(af, bf, acc[nt], 0, 0, 0);
    }
    __syncthreads();
  }

#pragma unroll
  for (int nt = 0; nt < 4; ++nt) {
    int col = N0 + nt * 16 + colb;
#pragma unroll
    for (int rr = 0; rr < 4; ++rr) {
      int row = I0 + w * 16 + rowb + rr;
      Out[(size_t)row * DD + col] = acc[nt][rr];
    }
  }
}

extern "C" void kernel_launch(void* const* d_in, const int* in_sizes, int n_in,
                              void* d_out, int out_size, void* d_ws, size_t ws_size,
                              hipStream_t stream) {
  const float* q  = (const float*)d_in[0];
  const float* k  = (const float*)d_in[1];
  const float* v  = (const float*)d_in[2];
  const float* wq = (const float*)d_in[3];
  const float* wk = (const float*)d_in[4];
  const float* wv = (const float*)d_in[5];
  const float* wo = (const float*)d_in[6];

  float* attn   = (float*)d_out;                              // (B,H,L,L)
  float* ctxout = (float*)d_out + (size_t)BHm * LL * LL;      // (B,L,D)

  // workspace: 4 bf16 buffers of 4M elems each = 32 MB total
  unsigned short* Qh  = (unsigned short*)d_ws;
  unsigned short* Kh  = Qh + (size_t)BHm * LL * HDm;
  unsigned short* Vt  = Kh + (size_t)BHm * LL * HDm;
  unsigned short* Ctx = Vt + (size_t)BHm * LL * HDm;

  k_proj_qkv<<<dim3(64, 16, 3), 256, 0, stream>>>(q, k, v, wq, wk, wv, Qh, Kh, Vt);
  k_attn<<<dim3(32, 32), 256, 0, stream>>>(Qh, Kh, Vt, attn, Ctx);
  k_out<<<dim3(64, 16), 256, 0, stream>>>(Ctx, wo, ctxout);
}

// Round 7
// 970.285 us; speedup vs baseline: 1.0199x; 1.0199x over previous
//
#include <hip/hip_runtime.h>
#include <hip/hip_bf16.h>

#define LL 2048
#define DD 1024
#define HH 16

typedef __attribute__((ext_vector_type(8))) short short8;
typedef __attribute__((ext_vector_type(4))) float floatx4;

// workspace layout (bf16 elements), total 32M el = 64 MB
#define OFF_XQ 0ul
#define OFF_XK 4194304ul
#define OFF_XV 8388608ul
#define OFF_WQ 12582912ul
#define OFF_WK 13631488ul
#define OFF_WV 14680064ul
#define OFF_WO 15728640ul
#define OFF_QH 16777216ul
#define OFF_KH 20971520ul
#define OFF_VT 25165824ul
#define OFF_CT 29360128ul

__device__ __forceinline__ unsigned short f2bf(float f) {
  union { float f; unsigned int u; } v; v.f = f;
  unsigned int r = v.u + 0x7fffu + ((v.u >> 16) & 1u);
  return (unsigned short)(r >> 16);
}

__device__ __forceinline__ short8 pack8(float4 a, float4 b) {
  short8 s;
  s[0]=(short)f2bf(a.x); s[1]=(short)f2bf(a.y); s[2]=(short)f2bf(a.z); s[3]=(short)f2bf(a.w);
  s[4]=(short)f2bf(b.x); s[5]=(short)f2bf(b.y); s[6]=(short)f2bf(b.z); s[7]=(short)f2bf(b.w);
  return s;
}

#define GLOAD_LDS16(g, l)                                            \
  __builtin_amdgcn_global_load_lds(                                  \
      (const __attribute__((address_space(1))) void*)(g),            \
      (__attribute__((address_space(3))) void*)(l), 16, 0, 0)

// ---------------- Kernel 0: f32 -> bf16 convert ----------------
__global__ __launch_bounds__(256) void k_cvt(
    const float* __restrict__ x0, const float* __restrict__ x1, const float* __restrict__ x2,
    const float* __restrict__ w0, const float* __restrict__ w1, const float* __restrict__ w2,
    const float* __restrict__ w3, unsigned short* __restrict__ ws)
{
  const int y = blockIdx.y;
  const float* src; unsigned short* dst; int n;
  switch (y) {
    case 0: src = x0; dst = ws + OFF_XQ; n = 4194304; break;
    case 1: src = x1; dst = ws + OFF_XK; n = 4194304; break;
    case 2: src = x2; dst = ws + OFF_XV; n = 4194304; break;
    case 3: src = w0; dst = ws + OFF_WQ; n = 1048576; break;
    case 4: src = w1; dst = ws + OFF_WK; n = 1048576; break;
    case 5: src = w2; dst = ws + OFF_WV; n = 1048576; break;
    default: src = w3; dst = ws + OFF_WO; n = 1048576; break;
  }
  int i = (blockIdx.x * 256 + threadIdx.x) * 8;
  if (i >= n) return;
  const float4* p = reinterpret_cast<const float4*>(src + i);
  *reinterpret_cast<short8*>(dst + i) = pack8(p[0], p[1]);
}

// ---------------- Kernel 1: bf16 NT GEMM, 128x64 tile, BK=64 ----------------
// A [4096][1024] bf16 K-contig; B [1024][1024] bf16 K-contig (rows = out cols).
// MODE 0: dst = head-split [b][h][l][hd] bf16 (Qh/Kh)
// MODE 2: dst = transposed [b][h][hd][l] bf16 (Vt)
// MODE 3: dst = plain f32 [row][col] (final output projection)
template<int MODE>
__global__ __launch_bounds__(256) void k_gemm(
    const unsigned short* __restrict__ A,
    const unsigned short* __restrict__ B,
    void* __restrict__ dstv)
{
  const int I0 = blockIdx.x * 128;
  const int N0 = blockIdx.y * 64;
  const int tid = threadIdx.x;
  const int lane = tid & 63;
  const int w = tid >> 6;
  const int wr = w >> 1, wc = w & 1;
  const int colb = lane & 15;
  const int rowb = (lane >> 4) * 4;
  const int kseg = (lane >> 4) * 8;

  __shared__ unsigned short Abuf[128 * 64];  // 16 KB
  __shared__ unsigned short Bbuf[64 * 64];   // 8 KB

  floatx4 acc[4][2] = {};

  for (int k0 = 0; k0 < DD; k0 += 64) {
#pragma unroll
    for (int i = 0; i < 4; ++i) {
      int e = (i * 4 + w) * 512 + lane * 8;
      const unsigned short* g = A + (size_t)(I0 + (e >> 6)) * DD + k0 + (e & 63);
      GLOAD_LDS16(g, Abuf + (i * 4 + w) * 512);
    }
#pragma unroll
    for (int i = 0; i < 2; ++i) {
      int e = (i * 4 + w) * 512 + lane * 8;
      const unsigned short* g = B + (size_t)(N0 + (e >> 6)) * DD + k0 + (e & 63);
      GLOAD_LDS16(g, Bbuf + (i * 4 + w) * 512);
    }
    __syncthreads();   // compiler drains vmcnt(0) here
#pragma unroll
    for (int kk = 0; kk < 2; ++kk) {
      short8 ar[4], br[2];
#pragma unroll
      for (int mi = 0; mi < 4; ++mi)
        ar[mi] = *reinterpret_cast<const short8*>(
            &Abuf[(wr * 64 + mi * 16 + colb) * 64 + kk * 32 + kseg]);
#pragma unroll
      for (int ni = 0; ni < 2; ++ni)
        br[ni] = *reinterpret_cast<const short8*>(
            &Bbuf[(wc * 32 + ni * 16 + colb) * 64 + kk * 32 + kseg]);
#pragma unroll
      for (int mi = 0; mi < 4; ++mi)
#pragma unroll
        for (int ni = 0; ni < 2; ++ni)
          acc[mi][ni] = __builtin_amdgcn_mfma_f32_16x16x32_bf16(ar[mi], br[ni], acc[mi][ni], 0, 0, 0);
    }
    __syncthreads();
  }

#pragma unroll
  for (int mi = 0; mi < 4; ++mi) {
#pragma unroll
    for (int ni = 0; ni < 2; ++ni) {
      int col = N0 + wc * 32 + ni * 16 + colb;
#pragma unroll
      for (int rr = 0; rr < 4; ++rr) {
        int row = I0 + wr * 64 + mi * 16 + rowb + rr;
        if (MODE == 3) {
          ((float*)dstv)[(size_t)row * DD + col] = acc[mi][ni][rr];
        } else {
          unsigned short val = f2bf(acc[mi][ni][rr]);
          int h = col >> 6, hd = col & 63;
          int b = row >> 11, l = row & 2047;
          unsigned short* dst = (unsigned short*)dstv;
          if (MODE == 0)
            dst[(((size_t)(b * HH + h)) * LL + l) * 64 + hd] = val;
          else
            dst[(((size_t)(b * HH + h)) * 64 + hd) * LL + l] = val;
        }
      }
    }
  }
}

// ---------------- Kernel 2: fused causal attention ----------------
// grid (32 qtiles, 32 bh); 4 waves, each owns 16 q-rows; NO barriers (per-wave LDS).
// Pass A: QK^T -> exp -> P(bf16,LDS) -> row-sums via MFMA(ones) + PV MFMA.
// Pass B: recompute QK^T -> normalized p -> LDS f32 -> coalesced float4 stores.
__global__ __launch_bounds__(256) void k_attn(
    const unsigned short* __restrict__ Qh,
    const unsigned short* __restrict__ Kh,
    const unsigned short* __restrict__ Vt,
    float* __restrict__ attn,               // (BH, L, L) f32
    unsigned short* __restrict__ Ctx)       // (B, L, D) bf16
{
  const int qt = blockIdx.x;
  const int bh = blockIdx.y;
  const int b = bh >> 4, h = bh & 15;
  const int Q0 = qt * 64;
  const int tid = threadIdx.x;
  const int lane = tid & 63;
  const int w = tid >> 6;
  const int colb = lane & 15;
  const int rowb = (lane >> 4) * 4;
  const int kseg = (lane >> 4) * 8;
  const float scale = 0.125f;  // rsqrt(64)

  __shared__ float Pf[4][16 * 68];                     // 17408 B; per-wave region
  unsigned short* Plw = (unsigned short*)&Pf[w][0];    // bf16 view, stride 72
  float* Pfw = &Pf[w][0];                              // f32 view, stride 68

  const unsigned short* Qbase = Qh + (size_t)bh * LL * 64;
  const unsigned short* Kbase = Kh + (size_t)bh * LL * 64;
  const unsigned short* Vbase = Vt + (size_t)bh * 64 * LL;

  const int qrow = Q0 + w * 16 + colb;
  short8 qf0 = *reinterpret_cast<const short8*>(Qbase + (size_t)qrow * 64 + kseg);
  short8 qf1 = *reinterpret_cast<const short8*>(Qbase + (size_t)qrow * 64 + 32 + kseg);

  short8 ones;
#pragma unroll
  for (int j = 0; j < 8; ++j) ones[j] = (short)0x3F80;  // bf16 1.0

  floatx4 ssum = {};
  floatx4 cacc[4] = {};

  // ---- Pass A ----
  for (int kt = 0; kt <= qt; ++kt) {
    const int K0 = kt * 64;
    floatx4 sacc[4] = {};
#pragma unroll
    for (int nt = 0; nt < 4; ++nt) {
      const unsigned short* kp = Kbase + (size_t)(K0 + nt * 16 + colb) * 64 + kseg;
      short8 kf0 = *reinterpret_cast<const short8*>(kp);
      short8 kf1 = *reinterpret_cast<const short8*>(kp + 32);
      sacc[nt] = __builtin_amdgcn_mfma_f32_16x16x32_bf16(qf0, kf0, sacc[nt], 0, 0, 0);
      sacc[nt] = __builtin_amdgcn_mfma_f32_16x16x32_bf16(qf1, kf1, sacc[nt], 0, 0, 0);
    }
#pragma unroll
    for (int nt = 0; nt < 4; ++nt) {
      int col = K0 + nt * 16 + colb;
#pragma unroll
      for (int rr = 0; rr < 4; ++rr) {
        int row = Q0 + w * 16 + rowb + rr;
        float sv = sacc[nt][rr] * scale;
        float e = ((col > row) || (sv == 0.0f)) ? 0.0f : __expf(sv);
        Plw[(rowb + rr) * 72 + nt * 16 + colb] = f2bf(e);
      }
    }
#pragma unroll
    for (int s = 0; s < 2; ++s) {
      short8 pf = *reinterpret_cast<const short8*>(&Plw[colb * 72 + s * 32 + kseg]);
      ssum = __builtin_amdgcn_mfma_f32_16x16x32_bf16(pf, ones, ssum, 0, 0, 0);
#pragma unroll
      for (int nt = 0; nt < 4; ++nt) {
        const unsigned short* vp = Vbase + (size_t)(nt * 16 + colb) * LL + K0 + s * 32 + kseg;
        short8 vf = *reinterpret_cast<const short8*>(vp);
        cacc[nt] = __builtin_amdgcn_mfma_f32_16x16x32_bf16(pf, vf, cacc[nt], 0, 0, 0);
      }
    }
  }

  float inv[4];
#pragma unroll
  for (int rr = 0; rr < 4; ++rr) inv[rr] = 1.0f / ssum[rr];

  // ---- context tile write ----
#pragma unroll
  for (int nt = 0; nt < 4; ++nt) {
    int col = h * 64 + nt * 16 + colb;
#pragma unroll
    for (int rr = 0; rr < 4; ++rr) {
      int row = Q0 + w * 16 + rowb + rr;
      Ctx[((size_t)b * LL + row) * DD + col] = f2bf(cacc[nt][rr] * inv[rr]);
    }
  }

  // ---- Pass B: write normalized probs (coalesced via LDS f32 bounce) ----
  for (int kt = 0; kt <= qt; ++kt) {
    const int K0 = kt * 64;
    floatx4 sacc[4] = {};
#pragma unroll
    for (int nt = 0; nt < 4; ++nt) {
      const unsigned short* kp = Kbase + (size_t)(K0 + nt * 16 + colb) * 64 + kseg;
      short8 kf0 = *reinterpret_cast<const short8*>(kp);
      short8 kf1 = *reinterpret_cast<const short8*>(kp + 32);
      sacc[nt] = __builtin_amdgcn_mfma_f32_16x16x32_bf16(qf0, kf0, sacc[nt], 0, 0, 0);
      sacc[nt] = __builtin_amdgcn_mfma_f32_16x16x32_bf16(qf1, kf1, sacc[nt], 0, 0, 0);
    }
#pragma unroll
    for (int nt = 0; nt < 4; ++nt) {
      int col = K0 + nt * 16 + colb;
#pragma unroll
      for (int rr = 0; rr < 4; ++rr) {
        int row = Q0 + w * 16 + rowb + rr;
        float sv = sacc[nt][rr] * scale;
        float p = ((col > row) || (sv == 0.0f)) ? 0.0f : __expf(sv) * inv[rr];
        Pfw[(rowb + rr) * 68 + nt * 16 + colb] = p;
      }
    }
#pragma unroll
    for (int i = 0; i < 4; ++i) {
      int idx = i * 64 + lane;
      int prow = idx >> 4, c4 = idx & 15;
      float4 v = *reinterpret_cast<const float4*>(&Pfw[prow * 68 + c4 * 4]);
      *reinterpret_cast<float4*>(
          &attn[((size_t)bh * LL + Q0 + w * 16 + prow) * LL + K0 + c4 * 4]) = v;
    }
  }

  // ---- zero-fill strictly-upper tiles (d_out poisoned each run) ----
  const int C0 = (qt + 1) * 64;
  if (C0 < LL) {
    const int zl4 = (LL - C0) >> 2;
    const float4 z = make_float4(0.f, 0.f, 0.f, 0.f);
    for (int row = 0; row < 64; ++row) {
      float4* dst = reinterpret_cast<float4*>(attn + ((size_t)bh * LL + Q0 + row) * LL + C0);
      for (int c = tid; c < zl4; c += 256) dst[c] = z;
    }
  }
}

extern "C" void kernel_launch(void* const* d_in, const int* in_sizes, int n_in,
                              void* d_out, int out_size, void* d_ws, size_t ws_size,
                              hipStream_t stream) {
  const float* q  = (const float*)d_in[0];
  const float* k  = (const float*)d_in[1];
  const float* v  = (const float*)d_in[2];
  const float* wq = (const float*)d_in[3];
  const float* wk = (const float*)d_in[4];
  const float* wv = (const float*)d_in[5];
  const float* wo = (const float*)d_in[6];

  float* attn   = (float*)d_out;                         // (B,H,L,L)
  float* ctxout = (float*)d_out + (size_t)32 * LL * LL;  // (B,L,D)

  unsigned short* ws = (unsigned short*)d_ws;

  k_cvt<<<dim3(2048, 7), 256, 0, stream>>>(q, k, v, wq, wk, wv, wo, ws);
  k_gemm<0><<<dim3(32, 16), 256, 0, stream>>>(ws + OFF_XQ, ws + OFF_WQ, ws + OFF_QH);
  k_gemm<0><<<dim3(32, 16), 256, 0, stream>>>(ws + OFF_XK, ws + OFF_WK, ws + OFF_KH);
  k_gemm<2><<<dim3(32, 16), 256, 0, stream>>>(ws + OFF_XV, ws + OFF_WV, ws + OFF_VT);
  k_attn<<<dim3(32, 32), 256, 0, stream>>>(ws + OFF_QH, ws + OFF_KH, ws + OFF_VT, attn, ws + OFF_CT);
  k_gemm<3><<<dim3(32, 16), 256, 0, stream>>>(ws + OFF_CT, ws + OFF_WO, ctxout);
}

// Round 8
// 946.859 us; speedup vs baseline: 1.0452x; 1.0247x over previous
//
#include <hip/hip_runtime.h>
#include <hip/hip_bf16.h>

#define LL 2048
#define DD 1024
#define HH 16

typedef __attribute__((ext_vector_type(8))) short short8;
typedef __attribute__((ext_vector_type(4))) float floatx4;

// workspace layout (bf16 elements), total 32M el = 64 MB
#define OFF_XQ 0ul
#define OFF_XK 4194304ul
#define OFF_XV 8388608ul
#define OFF_WQ 12582912ul
#define OFF_WK 13631488ul
#define OFF_WV 14680064ul
#define OFF_WO 15728640ul
#define OFF_QH 16777216ul
#define OFF_KH 20971520ul
#define OFF_VT 25165824ul
#define OFF_CT 29360128ul

__device__ __forceinline__ unsigned short f2bf(float f) {
  union { float f; unsigned int u; } v; v.f = f;
  unsigned int r = v.u + 0x7fffu + ((v.u >> 16) & 1u);
  return (unsigned short)(r >> 16);
}

__device__ __forceinline__ short8 pack8(float4 a, float4 b) {
  short8 s;
  s[0]=(short)f2bf(a.x); s[1]=(short)f2bf(a.y); s[2]=(short)f2bf(a.z); s[3]=(short)f2bf(a.w);
  s[4]=(short)f2bf(b.x); s[5]=(short)f2bf(b.y); s[6]=(short)f2bf(b.z); s[7]=(short)f2bf(b.w);
  return s;
}

#define GLOAD_LDS16(g, l)                                            \
  __builtin_amdgcn_global_load_lds(                                  \
      (const __attribute__((address_space(1))) void*)(g),            \
      (__attribute__((address_space(3))) void*)(l), 16, 0, 0)

// ---------------- Kernel 0: f32 -> bf16 convert ----------------
__global__ __launch_bounds__(256) void k_cvt(
    const float* __restrict__ x0, const float* __restrict__ x1, const float* __restrict__ x2,
    const float* __restrict__ w0, const float* __restrict__ w1, const float* __restrict__ w2,
    const float* __restrict__ w3, unsigned short* __restrict__ ws)
{
  const int y = blockIdx.y;
  const float* src; unsigned short* dst; int n;
  switch (y) {
    case 0: src = x0; dst = ws + OFF_XQ; n = 4194304; break;
    case 1: src = x1; dst = ws + OFF_XK; n = 4194304; break;
    case 2: src = x2; dst = ws + OFF_XV; n = 4194304; break;
    case 3: src = w0; dst = ws + OFF_WQ; n = 1048576; break;
    case 4: src = w1; dst = ws + OFF_WK; n = 1048576; break;
    case 5: src = w2; dst = ws + OFF_WV; n = 1048576; break;
    default: src = w3; dst = ws + OFF_WO; n = 1048576; break;
  }
  int i = (blockIdx.x * 256 + threadIdx.x) * 8;
  if (i >= n) return;
  const float4* p = reinterpret_cast<const float4*>(src + i);
  *reinterpret_cast<short8*>(dst + i) = pack8(p[0], p[1]);
}

// ---------------- Kernel 1: fused QKV GEMM ----------------
// 128x128 tile, BK=64, 4 waves (2x2), 4x4 16x16 frags/wave.
// LDS chunk-swizzle: LDS dest linear (global_load_lds), global SOURCE col-chunk
// pre-swizzled chunk^=(row&7); reads apply the same XOR (rule #21 both-sides).
// grid (32, 24): y>>3 = panel (0:Q 1:K 2:V), y&7 = 128-col tile within panel.
__global__ __launch_bounds__(256) void k_qkv(unsigned short* __restrict__ ws)
{
  const int panel = blockIdx.y >> 3;
  const int N0 = (blockIdx.y & 7) * 128;
  const int I0 = blockIdx.x * 128;

  const unsigned short* A = ws + (panel == 0 ? OFF_XQ : panel == 1 ? OFF_XK : OFF_XV);
  const unsigned short* B = ws + (panel == 0 ? OFF_WQ : panel == 1 ? OFF_WK : OFF_WV);

  const int tid = threadIdx.x;
  const int lane = tid & 63;
  const int w = tid >> 6;
  const int wr = w >> 1, wc = w & 1;
  const int colb = lane & 15;
  const int grp = lane >> 4;
  const int rowb = grp * 4;

  __shared__ unsigned short Abuf[128 * 64];  // 16 KB
  __shared__ unsigned short Bbuf[128 * 64];  // 16 KB

  floatx4 acc[4][4] = {};
  const int sr = tid >> 3;     // 0..31: row within 32-row staging round
  const int sch = tid & 7;     // 16B chunk 0..7 within 128B row

  for (int k0 = 0; k0 < DD; k0 += 64) {
#pragma unroll
    for (int i = 0; i < 4; ++i) {
      int r = i * 32 + sr;
      GLOAD_LDS16(A + (size_t)(I0 + r) * DD + k0 + ((sch ^ (r & 7)) * 8),
                  Abuf + i * 2048 + w * 512);
    }
#pragma unroll
    for (int i = 0; i < 4; ++i) {
      int r = i * 32 + sr;
      GLOAD_LDS16(B + (size_t)(N0 + r) * DD + k0 + ((sch ^ (r & 7)) * 8),
                  Bbuf + i * 2048 + w * 512);
    }
    __syncthreads();
#pragma unroll
    for (int kk = 0; kk < 2; ++kk) {
      short8 af[4], bf[4];
#pragma unroll
      for (int mi = 0; mi < 4; ++mi) {
        int row = wr * 64 + mi * 16 + colb;
        af[mi] = *reinterpret_cast<const short8*>(
            &Abuf[row * 64 + ((kk * 4 + grp) ^ (row & 7)) * 8]);
      }
#pragma unroll
      for (int ni = 0; ni < 4; ++ni) {
        int row = wc * 64 + ni * 16 + colb;
        bf[ni] = *reinterpret_cast<const short8*>(
            &Bbuf[row * 64 + ((kk * 4 + grp) ^ (row & 7)) * 8]);
      }
#pragma unroll
      for (int mi = 0; mi < 4; ++mi)
#pragma unroll
        for (int ni = 0; ni < 4; ++ni)
          acc[mi][ni] = __builtin_amdgcn_mfma_f32_16x16x32_bf16(af[mi], bf[ni], acc[mi][ni], 0, 0, 0);
    }
    __syncthreads();
  }

  unsigned short* dstQK = ws + (panel == 0 ? OFF_QH : OFF_KH);
  unsigned short* dstV = ws + OFF_VT;
#pragma unroll
  for (int mi = 0; mi < 4; ++mi) {
#pragma unroll
    for (int ni = 0; ni < 4; ++ni) {
      int c = N0 + wc * 64 + ni * 16 + colb;   // 0..1023 within panel
      int h = c >> 6, hd = c & 63;
#pragma unroll
      for (int rr = 0; rr < 4; ++rr) {
        int row = I0 + wr * 64 + mi * 16 + rowb + rr;
        int b = row >> 11, l = row & 2047;
        unsigned short val = f2bf(acc[mi][ni][rr]);
        if (panel < 2)
          dstQK[(((size_t)(b * HH + h)) * LL + l) * 64 + hd] = val;
        else
          dstV[(((size_t)(b * HH + h)) * 64 + hd) * LL + l] = val;
      }
    }
  }
}

// ---------------- Kernel 3: output projection (same 128x128 template) ----------------
__global__ __launch_bounds__(256) void k_out(
    const unsigned short* __restrict__ Ctx, const unsigned short* __restrict__ Wo,
    float* __restrict__ Out)
{
  const int N0 = blockIdx.y * 128;
  const int I0 = blockIdx.x * 128;

  const int tid = threadIdx.x;
  const int lane = tid & 63;
  const int w = tid >> 6;
  const int wr = w >> 1, wc = w & 1;
  const int colb = lane & 15;
  const int grp = lane >> 4;
  const int rowb = grp * 4;

  __shared__ unsigned short Abuf[128 * 64];
  __shared__ unsigned short Bbuf[128 * 64];

  floatx4 acc[4][4] = {};
  const int sr = tid >> 3;
  const int sch = tid & 7;

  for (int k0 = 0; k0 < DD; k0 += 64) {
#pragma unroll
    for (int i = 0; i < 4; ++i) {
      int r = i * 32 + sr;
      GLOAD_LDS16(Ctx + (size_t)(I0 + r) * DD + k0 + ((sch ^ (r & 7)) * 8),
                  Abuf + i * 2048 + w * 512);
    }
#pragma unroll
    for (int i = 0; i < 4; ++i) {
      int r = i * 32 + sr;
      GLOAD_LDS16(Wo + (size_t)(N0 + r) * DD + k0 + ((sch ^ (r & 7)) * 8),
                  Bbuf + i * 2048 + w * 512);
    }
    __syncthreads();
#pragma unroll
    for (int kk = 0; kk < 2; ++kk) {
      short8 af[4], bf[4];
#pragma unroll
      for (int mi = 0; mi < 4; ++mi) {
        int row = wr * 64 + mi * 16 + colb;
        af[mi] = *reinterpret_cast<const short8*>(
            &Abuf[row * 64 + ((kk * 4 + grp) ^ (row & 7)) * 8]);
      }
#pragma unroll
      for (int ni = 0; ni < 4; ++ni) {
        int row = wc * 64 + ni * 16 + colb;
        bf[ni] = *reinterpret_cast<const short8*>(
            &Bbuf[row * 64 + ((kk * 4 + grp) ^ (row & 7)) * 8]);
      }
#pragma unroll
      for (int mi = 0; mi < 4; ++mi)
#pragma unroll
        for (int ni = 0; ni < 4; ++ni)
          acc[mi][ni] = __builtin_amdgcn_mfma_f32_16x16x32_bf16(af[mi], bf[ni], acc[mi][ni], 0, 0, 0);
    }
    __syncthreads();
  }

#pragma unroll
  for (int mi = 0; mi < 4; ++mi) {
#pragma unroll
    for (int ni = 0; ni < 4; ++ni) {
      int col = N0 + wc * 64 + ni * 16 + colb;
#pragma unroll
      for (int rr = 0; rr < 4; ++rr) {
        int row = I0 + wr * 64 + mi * 16 + rowb + rr;
        Out[(size_t)row * DD + col] = acc[mi][ni][rr];
      }
    }
  }
}

// ---------------- Kernel 2: fused causal attention ----------------
// grid (32 qtiles, 32 bh); 4 waves, each owns 16 q-rows; NO barriers (per-wave LDS).
// Pass A: QK^T -> exp -> P(bf16,LDS) -> row-sums via MFMA(ones) + PV MFMA.
// Pass B: recompute QK^T -> normalized p -> LDS f32 -> coalesced float4 stores.
__global__ __launch_bounds__(256) void k_attn(
    const unsigned short* __restrict__ Qh,
    const unsigned short* __restrict__ Kh,
    const unsigned short* __restrict__ Vt,
    float* __restrict__ attn,               // (BH, L, L) f32
    unsigned short* __restrict__ Ctx)       // (B, L, D) bf16
{
  const int qt = blockIdx.x;
  const int bh = blockIdx.y;
  const int b = bh >> 4, h = bh & 15;
  const int Q0 = qt * 64;
  const int tid = threadIdx.x;
  const int lane = tid & 63;
  const int w = tid >> 6;
  const int colb = lane & 15;
  const int rowb = (lane >> 4) * 4;
  const int kseg = (lane >> 4) * 8;
  const float CE = 0.18033688011112042f;  // 0.125 * log2(e): exp(s*0.125)=exp2(s*CE)

  __shared__ float Pf[4][16 * 68];                     // 17408 B; per-wave region
  unsigned short* Plw = (unsigned short*)&Pf[w][0];    // bf16 view, stride 72
  float* Pfw = &Pf[w][0];                              // f32 view, stride 68

  const unsigned short* Qbase = Qh + (size_t)bh * LL * 64;
  const unsigned short* Kbase = Kh + (size_t)bh * LL * 64;
  const unsigned short* Vbase = Vt + (size_t)bh * 64 * LL;

  const int qrow = Q0 + w * 16 + colb;
  short8 qf0 = *reinterpret_cast<const short8*>(Qbase + (size_t)qrow * 64 + kseg);
  short8 qf1 = *reinterpret_cast<const short8*>(Qbase + (size_t)qrow * 64 + 32 + kseg);

  short8 ones;
#pragma unroll
  for (int j = 0; j < 8; ++j) ones[j] = (short)0x3F80;  // bf16 1.0

  floatx4 ssum = {};
  floatx4 cacc[4] = {};

  // ---- Pass A ----
  for (int kt = 0; kt <= qt; ++kt) {
    const int K0 = kt * 64;
    floatx4 sacc[4] = {};
#pragma unroll
    for (int nt = 0; nt < 4; ++nt) {
      const unsigned short* kp = Kbase + (size_t)(K0 + nt * 16 + colb) * 64 + kseg;
      short8 kf0 = *reinterpret_cast<const short8*>(kp);
      short8 kf1 = *reinterpret_cast<const short8*>(kp + 32);
      sacc[nt] = __builtin_amdgcn_mfma_f32_16x16x32_bf16(qf0, kf0, sacc[nt], 0, 0, 0);
      sacc[nt] = __builtin_amdgcn_mfma_f32_16x16x32_bf16(qf1, kf1, sacc[nt], 0, 0, 0);
    }
#pragma unroll
    for (int nt = 0; nt < 4; ++nt) {
      int col = K0 + nt * 16 + colb;
#pragma unroll
      for (int rr = 0; rr < 4; ++rr) {
        int row = Q0 + w * 16 + rowb + rr;
        float raw = sacc[nt][rr];
        float e = ((col > row) || (raw == 0.0f)) ? 0.0f : exp2f(raw * CE);
        Plw[(rowb + rr) * 72 + nt * 16 + colb] = f2bf(e);
      }
    }
#pragma unroll
    for (int s = 0; s < 2; ++s) {
      short8 pf = *reinterpret_cast<const short8*>(&Plw[colb * 72 + s * 32 + kseg]);
      ssum = __builtin_amdgcn_mfma_f32_16x16x32_bf16(pf, ones, ssum, 0, 0, 0);
#pragma unroll
      for (int nt = 0; nt < 4; ++nt) {
        const unsigned short* vp = Vbase + (size_t)(nt * 16 + colb) * LL + K0 + s * 32 + kseg;
        short8 vf = *reinterpret_cast<const short8*>(vp);
        cacc[nt] = __builtin_amdgcn_mfma_f32_16x16x32_bf16(pf, vf, cacc[nt], 0, 0, 0);
      }
    }
  }

  float inv[4];
#pragma unroll
  for (int rr = 0; rr < 4; ++rr) inv[rr] = 1.0f / ssum[rr];

  // ---- context tile write ----
#pragma unroll
  for (int nt = 0; nt < 4; ++nt) {
    int col = h * 64 + nt * 16 + colb;
#pragma unroll
    for (int rr = 0; rr < 4; ++rr) {
      int row = Q0 + w * 16 + rowb + rr;
      Ctx[((size_t)b * LL + row) * DD + col] = f2bf(cacc[nt][rr] * inv[rr]);
    }
  }

  // ---- Pass B: write normalized probs (coalesced via LDS f32 bounce) ----
  for (int kt = 0; kt <= qt; ++kt) {
    const int K0 = kt * 64;
    floatx4 sacc[4] = {};
#pragma unroll
    for (int nt = 0; nt < 4; ++nt) {
      const unsigned short* kp = Kbase + (size_t)(K0 + nt * 16 + colb) * 64 + kseg;
      short8 kf0 = *reinterpret_cast<const short8*>(kp);
      short8 kf1 = *reinterpret_cast<const short8*>(kp + 32);
      sacc[nt] = __builtin_amdgcn_mfma_f32_16x16x32_bf16(qf0, kf0, sacc[nt], 0, 0, 0);
      sacc[nt] = __builtin_amdgcn_mfma_f32_16x16x32_bf16(qf1, kf1, sacc[nt], 0, 0, 0);
    }
#pragma unroll
    for (int nt = 0; nt < 4; ++nt) {
      int col = K0 + nt * 16 + colb;
#pragma unroll
      for (int rr = 0; rr < 4; ++rr) {
        int row = Q0 + w * 16 + rowb + rr;
        float raw = sacc[nt][rr];
        float p = ((col > row) || (raw == 0.0f)) ? 0.0f : exp2f(raw * CE) * inv[rr];
        Pfw[(rowb + rr) * 68 + nt * 16 + colb] = p;
      }
    }
#pragma unroll
    for (int i = 0; i < 4; ++i) {
      int idx = i * 64 + lane;
      int prow = idx >> 4, c4 = idx & 15;
      float4 v = *reinterpret_cast<const float4*>(&Pfw[prow * 68 + c4 * 4]);
      *reinterpret_cast<float4*>(
          &attn[((size_t)bh * LL + Q0 + w * 16 + prow) * LL + K0 + c4 * 4]) = v;
    }
  }

  // ---- zero-fill strictly-upper tiles (d_out poisoned each run) ----
  const int C0 = (qt + 1) * 64;
  if (C0 < LL) {
    const int zl4 = (LL - C0) >> 2;
    const float4 z = make_float4(0.f, 0.f, 0.f, 0.f);
    for (int row = 0; row < 64; ++row) {
      float4* dst = reinterpret_cast<float4*>(attn + ((size_t)bh * LL + Q0 + row) * LL + C0);
      for (int c = tid; c < zl4; c += 256) dst[c] = z;
    }
  }
}

extern "C" void kernel_launch(void* const* d_in, const int* in_sizes, int n_in,
                              void* d_out, int out_size, void* d_ws, size_t ws_size,
                              hipStream_t stream) {
  const float* q  = (const float*)d_in[0];
  const float* k  = (const float*)d_in[1];
  const float* v  = (const float*)d_in[2];
  const float* wq = (const float*)d_in[3];
  const float* wk = (const float*)d_in[4];
  const float* wv = (const float*)d_in[5];
  const float* wo = (const float*)d_in[6];

  float* attn   = (float*)d_out;                         // (B,H,L,L)
  float* ctxout = (float*)d_out + (size_t)32 * LL * LL;  // (B,L,D)

  unsigned short* ws = (unsigned short*)d_ws;

  k_cvt<<<dim3(2048, 7), 256, 0, stream>>>(q, k, v, wq, wk, wv, wo, ws);
  k_qkv<<<dim3(32, 24), 256, 0, stream>>>(ws);
  k_attn<<<dim3(32, 32), 256, 0, stream>>>(ws + OFF_QH, ws + OFF_KH, ws + OFF_VT, attn, ws + OFF_CT);
  k_out<<<dim3(32, 8), 256, 0, stream>>>(ws + OFF_CT, ws + OFF_WO, ctxout);
}